// Round 8
// baseline (547.150 us; speedup 1.0000x reference)
//
#include <hip/hip_runtime.h>
#include <cstdint>
#include <cstddef>

typedef _Float16 f16;
typedef _Float16 f16x8 __attribute__((ext_vector_type(8)));
typedef float f32x4 __attribute__((ext_vector_type(4)));

// ---------------------------------------------------------------------------
// W is stored fragment-tiled for mfma_f32_16x16x32_f16's B operand:
// lane l of a wave holds B[n = nf*16 + (l&15)][k = kb*32 + (l>>4)*8 + j].
// Element (n,k) lives at flat f16 index
//   ((n>>4)*(K/32) + (k>>5))*512 + (((k>>3)&3)*16 + (n&15))*8 + (k&7)
// so a wave loads one fragment as ONE coalesced global_load_dwordx4.
// ---------------------------------------------------------------------------

// Wt tile for coef: k = i*8+g  ->  kb=i>>2, lane=(i&3)*16+(o&15), elem g
template <int I, int O>
__global__ void prep_coef(const float* __restrict__ coef,
                          const float* __restrict__ ssp,
                          f16* __restrict__ Wt) {
  constexpr int K32 = (9 * I) / 32;
  int tid = blockIdx.x * 256 + threadIdx.x;
  if (tid >= I * O) return;
  int i = tid / O, o = tid % O;             // o fastest -> coalesced coef reads
  float s = ssp[tid];
  const float* c = coef + (size_t)tid * 8;
  f16x8 out;
#pragma unroll
  for (int g = 0; g < 8; ++g) out[g] = (f16)(c[g] * s);
  size_t addr = ((size_t)(o >> 4) * K32 + (i >> 2)) * 512 +
                (size_t)(((i & 3) * 16) + (o & 15)) * 8;
  *(f16x8*)(Wt + addr) = out;
}

// Wt tile for base: k = 8I+i -> kb=I/4+(i>>5), lane=((i>>3)&3)*16+(o&15)
template <int I, int O>
__global__ void prep_base(const float* __restrict__ sb, f16* __restrict__ Wt) {
  constexpr int K32 = (9 * I) / 32;
  int tid = blockIdx.x * 256 + threadIdx.x;
  if (tid >= (I / 8) * O) return;
  int i8 = tid / O, o = tid % O;            // o fastest -> coalesced writes
  f16x8 out;
#pragma unroll
  for (int s = 0; s < 8; ++s)
    out[s] = (f16)sb[(size_t)(i8 * 8 + s) * O + o];
  size_t addr = ((size_t)(o >> 4) * K32 + (I / 4) + (i8 >> 2)) * 512 +
                (size_t)(((i8 & 3) * 16) + (o & 15)) * 8;
  *(f16x8*)(Wt + addr) = out;
}

// ---------------------------------------------------------------------------
// 8-slot cubic B-spline basis, packed-shift form (verified R6/R7, 0.0625).
// ---------------------------------------------------------------------------
__device__ __forceinline__ f16x8 spline8(float h) {
  float v = __builtin_fmaf(2.5f, h, 5.5f);
  float c = floorf(v);
  float f = v - c;
  float f2 = f * f, f3 = f2 * f;
  float b3 = f3 * (1.f / 6.f);
  float t = 1.f - f;
  float b0 = t * t * t * (1.f / 6.f);
  float b1 = (2.f / 3.f) - f2 + 0.5f * f3;
  float b2 = 1.f - b0 - b1 - b3;
  unsigned int u01 =
      __builtin_bit_cast(unsigned int, __builtin_amdgcn_cvt_pkrtz(b0, b1));
  unsigned int u23 =
      __builtin_bit_cast(unsigned int, __builtin_amdgcn_cvt_pkrtz(b2, b3));
  unsigned long long pk = (unsigned long long)u01 |
                          ((unsigned long long)u23 << 32);
  int ci = (int)c;
  int s = (ci - 3) * 16;                // bit offset of slot c-3
  __uint128_t r = 0;
  if (s >= 0) {
    if (s < 128) r = (__uint128_t)pk << s;
  } else {
    int q = -s;
    if (q < 64) r = (__uint128_t)(pk >> q);
  }
  return __builtin_bit_cast(f16x8, r);
}

// ---------------------------------------------------------------------------
// Fused KAN GEMM, 128(M) x 256(N) tile, BK=64, software-pipelined A.
// R7 post-mortem: 2 waves/SIMD (256-reg lock) + serial [A-gen|barrier|MFMA|
// barrier] chain pinned us at 27% MFMA regardless of per-phase cost. R8:
// double-buffered sA, ONE barrier per k-tile, A(k+1) generated in the MFMA
// shadow of k (same-wave MFMA/VALU dual-issue), B-fragments straight from
// global (fragment-tiled W, L2-resident), H prefetched one tile ahead.
// All vm-loads are consumed before the barrier -> its vmcnt(0) drain is free.
// ---------------------------------------------------------------------------
template <int I, int ATOMIC>
__global__ __launch_bounds__(256, 2) void gemm_kan(const float* __restrict__ H,
                                                   const f16* __restrict__ W,
                                                   float* __restrict__ C,
                                                   int N, int kChunk) {
  constexpr int K = 9 * I;
  constexpr int KB = 8 * I;                   // spline/base boundary (mult 64)
  constexpr int K32 = K / 32;
  __shared__ __align__(16) f16 sA[2][128 * 64];  // 32 KB double buffer
  const int t = threadIdx.x;
  const int n0 = blockIdx.x * 256;
  const int m0 = blockIdx.y * 128;
  const int kBeg = blockIdx.z * kChunk;
  const int kEnd = kBeg + kChunk;
  const int w = t >> 6, lane = t & 63;
  const int wm = (w >> 1) * 64, wn = (w & 1) * 128;
  const int lr = lane & 15, lq = lane >> 4;
  const int srow = t >> 3;                    // staging row 0..31 (q adds 32)
  const int j_ = t & 7;                       // chunk col 0..7
  const int js = j_ ^ (srow & 7);             // swizzled chunk col

  f32x4 acc[4][8] = {};
  const float* Hrow = H + (size_t)(m0 + srow) * I;
  const f16* Pw = W + (size_t)((n0 + wn) >> 4) * K32 * 512 + lane * 8;
  const f16* Pwk = Pw + (size_t)(kBeg >> 5) * 512;

  // ---- prologue: generate A(kBeg) into buffer 0
  {
    f16x8 nx[4];
    if (kBeg < KB) {
      const int i0 = kBeg >> 3;
#pragma unroll
      for (int q = 0; q < 4; ++q) {
        float h = Hrow[(size_t)(q * 32) * I + i0 + j_];
        nx[q] = spline8(h);
      }
    } else {
      const int c0 = (kBeg - KB) + j_ * 8;
#pragma unroll
      for (int q = 0; q < 4; ++q) {
        const f32x4* pp = (const f32x4*)(Hrow + (size_t)(q * 32) * I + c0);
        f32x4 a0 = pp[0], a1 = pp[1];
        f16x8 o;
#pragma unroll
        for (int s = 0; s < 8; ++s) {
          float h = (s < 4) ? a0[s & 3] : a1[s & 3];
          o[s] = (f16)(h / (1.f + __expf(-h)));
        }
        nx[q] = o;
      }
    }
#pragma unroll
    for (int q = 0; q < 4; ++q)
      *(f16x8*)&sA[0][((q * 32 + srow) * 8 + js) * 8] = nx[q];
  }
  __syncthreads();

  int p = 0;
  for (int k0 = kBeg; k0 < kEnd; k0 += 64, p ^= 1) {
    const f16* curA = &sA[p][0];
    // B frags, both kk halves — issue first (latency under everything below)
    f16x8 bv0[8], bv1[8];
#pragma unroll
    for (int j = 0; j < 8; ++j) {
      bv0[j] = *(const f16x8*)(Pwk + (size_t)j * (K32 * 512));
      bv1[j] = *(const f16x8*)(Pwk + (size_t)j * (K32 * 512) + 512);
    }

    // H prefetch for tile k0+64 (uniform branch). Spline: 4 scalars, convert
    // later in the MFMA shadow. Silu: convert eagerly to cap live VGPRs.
    const int kn = k0 + 64;
    const bool more = kn < kEnd;
    float hs[4];
    f16x8 nx[4];
    bool nspline = false;
    if (more) {
      if (kn < KB) {
        nspline = true;
        const int i0n = kn >> 3;
#pragma unroll
        for (int q = 0; q < 4; ++q)
          hs[q] = Hrow[(size_t)(q * 32) * I + i0n + j_];
      } else {
        const int c0 = (kn - KB) + j_ * 8;
#pragma unroll
        for (int q = 0; q < 4; ++q) {
          const f32x4* pp = (const f32x4*)(Hrow + (size_t)(q * 32) * I + c0);
          f32x4 a0 = pp[0], a1 = pp[1];
          f16x8 o;
#pragma unroll
          for (int s = 0; s < 8; ++s) {
            float h = (s < 4) ? a0[s & 3] : a1[s & 3];
            o[s] = (f16)(h / (1.f + __expf(-h)));
          }
          nx[q] = o;
        }
      }
    }

    // av kk=0 + MFMA half 1
    f16x8 av[4];
#pragma unroll
    for (int i = 0; i < 4; ++i) {
      const int ra = wm + i * 16 + lr;
      const int ca = lq ^ (ra & 7);
      av[i] = *(const f16x8*)&curA[ra * 64 + ca * 8];
    }
#pragma unroll
    for (int i = 0; i < 4; ++i)
#pragma unroll
      for (int j = 0; j < 8; ++j)
        acc[i][j] = __builtin_amdgcn_mfma_f32_16x16x32_f16(av[i], bv0[j],
                                                           acc[i][j], 0, 0, 0);

    // spline for tile k0+64, in the MFMA-half-1 shadow (VALU co-issue)
    if (nspline) {
#pragma unroll
      for (int q = 0; q < 4; ++q) nx[q] = spline8(hs[q]);
    }

    // av kk=32 + MFMA half 2
#pragma unroll
    for (int i = 0; i < 4; ++i) {
      const int ra = wm + i * 16 + lr;
      const int ca = (4 + lq) ^ (ra & 7);
      av[i] = *(const f16x8*)&curA[ra * 64 + ca * 8];
    }
#pragma unroll
    for (int i = 0; i < 4; ++i)
#pragma unroll
      for (int j = 0; j < 8; ++j)
        acc[i][j] = __builtin_amdgcn_mfma_f32_16x16x32_f16(av[i], bv1[j],
                                                           acc[i][j], 0, 0, 0);

    // stage A(k0+64) into the alternate buffer
    if (more) {
      f16* altA = &sA[p ^ 1][0];
#pragma unroll
      for (int q = 0; q < 4; ++q)
        *(f16x8*)&altA[((q * 32 + srow) * 8 + js) * 8] = nx[q];
    }
    Pwk += 1024;
    __syncthreads();
  }

#pragma unroll
  for (int i = 0; i < 4; ++i) {
#pragma unroll
    for (int j = 0; j < 8; ++j) {
      const int col = n0 + wn + j * 16 + lr;
#pragma unroll
      for (int r = 0; r < 4; ++r) {
        const int row = m0 + wm + i * 16 + lq * 4 + r;
        if (ATOMIC)
          atomicAdd(&C[(size_t)row * N + col], acc[i][j][r]);
        else
          C[(size_t)row * N + col] = acc[i][j][r];
      }
    }
  }
}

// ---------------------------------------------------------------------------
extern "C" void kernel_launch(void* const* d_in, const int* in_sizes, int n_in,
                              void* d_out, int out_size, void* d_ws,
                              size_t ws_size, hipStream_t stream) {
  const float* x     = (const float*)d_in[0];
  const float* coef1 = (const float*)d_in[1];
  const float* sb1   = (const float*)d_in[2];
  const float* ssp1  = (const float*)d_in[3];
  const float* coef2 = (const float*)d_in[4];
  const float* sb2   = (const float*)d_in[5];
  const float* ssp2  = (const float*)d_in[6];

  const int Mtot = 8192;
  const int I1 = 512, O1 = 2048, K1 = I1 * 9;   // 4608
  const int I2 = 2048, O2 = 512, K2 = I2 * 9;   // 18432

  char* ws = (char*)d_ws;
  const size_t szW1 = (size_t)O1 * K1 * sizeof(f16);     // 18.9 MB
  const size_t szW2 = (size_t)O2 * K2 * sizeof(f16);     // 18.9 MB
  const size_t szH  = (size_t)Mtot * O1 * sizeof(float); // 67.1 MB
  if (ws_size < szW1 + szW2 + szH) return;  // cannot run; fail visibly
  f16*   W1 = (f16*)ws;
  f16*   W2 = (f16*)(ws + szW1);
  float* h1 = (float*)(ws + szW1 + szW2);

  // weight prep (fragment-tiled layout)
  {
    int n1 = I1 * O1;
    prep_coef<512, 2048><<<(n1 + 255) / 256, 256, 0, stream>>>(coef1, ssp1, W1);
    prep_base<512, 2048><<<(n1 / 8 + 255) / 256, 256, 0, stream>>>(sb1, W1);
    int n2 = I2 * O2;
    prep_coef<2048, 512><<<(n2 + 255) / 256, 256, 0, stream>>>(coef2, ssp2, W2);
    prep_base<2048, 512><<<(n2 / 8 + 255) / 256, 256, 0, stream>>>(sb2, W2);
  }

  // layer 1: h1 = KanAct(x) @ W1^T   — grid 8x64 = 512 blocks, 2/CU
  gemm_kan<512, 0><<<dim3(O1 / 256, Mtot / 128, 1), 256, 0, stream>>>(
      x, W1, h1, O1, K1);

  // layer 2: out = KanAct(h1) @ W2^T — split-K=4, grid 2x64x4 = 512 blocks
  (void)hipMemsetAsync(d_out, 0, (size_t)Mtot * O2 * sizeof(float), stream);
  const int SK = 4;
  gemm_kan<2048, 1><<<dim3(O2 / 256, Mtot / 128, SK), 256, 0, stream>>>(
      h1, W2, (float*)d_out, O2, K2 / SK);
}